// Round 1
// baseline (31494.595 us; speedup 1.0000x reference)
//
#include <hip/hip_runtime.h>
#include <hip/hip_bf16.h>

// ---------------------------------------------------------------------------
// Continuous Thought Machine — round 0: correctness-first fp32 SIMT pipeline.
// B=64 S=512 F=1024 D_MODEL=2048 D_MEM=32 D_IN=1024 H=16 DH=64 D_OUT=1000
// N_SYNC=512 T=16 H_NLM=32
// ---------------------------------------------------------------------------

#define B_ 64
#define S_ 512
#define F_ 1024
#define DMODEL 2048
#define DMEM 32
#define DIN 1024
#define NH 16
#define DH 64
#define DOUT 1000
#define NSYNC 512
#define TICKS 16
#define HNLM 32
#define HIST_W 48  // 32 init + 16 appended

__device__ inline float to_f(float x) { return x; }
__device__ inline float to_f(__hip_bfloat16 x) { return __bfloat162float(x); }
__device__ inline void store_f(float* p, float v) { *p = v; }
__device__ inline void store_f(__hip_bfloat16* p, float v) { *p = __float2bfloat16(v); }

__device__ inline float gelu_f(float x) {
  float x3 = x * x * x;
  return 0.5f * x * (1.f + tanhf(0.7978845608028654f * (x + 0.044715f * x3)));
}

__device__ inline float bf_lo(unsigned v) { return __uint_as_float(v << 16); }
__device__ inline float bf_hi(unsigned v) { return __uint_as_float(v & 0xffff0000u); }

// ---------------- generic tiled GEMM: C = act(A @ B + bias) ----------------
// A: (M,K) row-major (TA), B: (K,N) row-major fp32, C: (M,N) row-major (TC)
// 256 threads; K % BK == 0 required (all our K are multiples of 16).
template <int BM, int BN, int BK, int TM, int TN, int ACT, typename TA, typename TC>
__global__ __launch_bounds__(256) void gemm_k(const TA* __restrict__ A,
                                              const float* __restrict__ B,
                                              const float* __restrict__ bias,
                                              TC* __restrict__ C, int M, int N, int K) {
  __shared__ float As[BK][BM + 1];
  __shared__ float Bs[BK][BN + 1];
  const int tid = threadIdx.x;
  const int brow = blockIdx.y * BM;
  const int bcol = blockIdx.x * BN;
  constexpr int NTC = BN / TN;  // threads along N
  const int tc = tid % NTC;
  const int tr = tid / NTC;
  float acc[TM][TN];
#pragma unroll
  for (int i = 0; i < TM; i++)
#pragma unroll
    for (int j = 0; j < TN; j++) acc[i][j] = 0.f;

  for (int k0 = 0; k0 < K; k0 += BK) {
    for (int i = tid; i < BM * BK; i += 256) {
      int r = i / BK, c = i % BK;
      int gr = brow + r;
      As[c][r] = (gr < M) ? to_f(A[(size_t)gr * K + k0 + c]) : 0.f;
    }
    for (int i = tid; i < BK * BN; i += 256) {
      int r = i / BN, c = i % BN;
      int gc = bcol + c;
      Bs[r][c] = (gc < N) ? B[(size_t)(k0 + r) * N + gc] : 0.f;
    }
    __syncthreads();
#pragma unroll
    for (int kk = 0; kk < BK; ++kk) {
      float a[TM], bb[TN];
#pragma unroll
      for (int i = 0; i < TM; i++) a[i] = As[kk][tr * TM + i];
#pragma unroll
      for (int j = 0; j < TN; j++) bb[j] = Bs[kk][tc * TN + j];
#pragma unroll
      for (int i = 0; i < TM; i++)
#pragma unroll
        for (int j = 0; j < TN; j++) acc[i][j] += a[i] * bb[j];
    }
    __syncthreads();
  }
#pragma unroll
  for (int i = 0; i < TM; i++) {
    int gr = brow + tr * TM + i;
    if (gr >= M) continue;
#pragma unroll
    for (int j = 0; j < TN; j++) {
      int gc = bcol + tc * TN + j;
      if (gc >= N) continue;
      float v = acc[i][j] + bias[gc];
      if (ACT == 1) v = gelu_f(v);
      store_f(&C[(size_t)gr * N + gc], v);
    }
  }
}

// ---------------- LayerNorm over last dim; strided/typed output ----------------
template <typename TOUT>
__global__ __launch_bounds__(256) void ln_kernel(const float* __restrict__ x,
                                                 const float* __restrict__ g,
                                                 const float* __restrict__ be,
                                                 TOUT* __restrict__ out, int C,
                                                 size_t row_stride, int col_stride) {
  const int row = blockIdx.x;
  const int tid = threadIdx.x;
  const float* xr = x + (size_t)row * C;
  float s = 0.f, s2 = 0.f;
  for (int c = tid; c < C; c += 256) {
    float v = xr[c];
    s += v;
    s2 += v * v;
  }
  __shared__ float r1[256], r2[256];
  r1[tid] = s;
  r2[tid] = s2;
  __syncthreads();
  for (int st = 128; st > 0; st >>= 1) {
    if (tid < st) {
      r1[tid] += r1[tid + st];
      r2[tid] += r2[tid + st];
    }
    __syncthreads();
  }
  float mean = r1[0] / C;
  float var = r2[0] / C - mean * mean;
  float inv = 1.0f / sqrtf(var + 1e-5f);
  for (int c = tid; c < C; c += 256) {
    float v = (xr[c] - mean) * inv * g[c] + be[c];
    store_f(&out[(size_t)row * row_stride + (size_t)c * col_stride], v);
  }
}

// ---------------- init kernels ----------------
__global__ void init_act_kernel(const float* __restrict__ init_state, float* __restrict__ act) {
  int i = blockIdx.x * 256 + threadIdx.x;  // B*DMODEL = 131072
  if (i < B_ * DMODEL) act[i] = init_state[i & (DMODEL - 1)];
}

__global__ void init_hist_kernel(const float* __restrict__ init_hist, float* __restrict__ hist) {
  int i = blockIdx.x * 256 + threadIdx.x;  // B*DMODEL*DMEM = 4194304
  if (i >= B_ * DMODEL * DMEM) return;
  int m = i & (DMEM - 1);
  int bd = i >> 5;  // b*DMODEL + d
  int d = bd & (DMODEL - 1);
  hist[(size_t)bd * HIST_W + m] = init_hist[d * DMEM + m];
}

__global__ void init_sync_kernel(const float* __restrict__ init_state,
                                 const int* __restrict__ lo, const int* __restrict__ ro,
                                 float* __restrict__ aA, float* __restrict__ bA,
                                 float* __restrict__ aO, float* __restrict__ bO) {
  int i = blockIdx.x * 256 + threadIdx.x;  // B*NSYNC = 32768
  if (i >= B_ * NSYNC) return;
  int j = i & (NSYNC - 1);
  aA[i] = 0.f;
  bA[i] = 0.f;
  aO[i] = init_state[lo[j]] * init_state[ro[j]];
  bO[i] = 1.f;
}

// ---------------- sync accumulator update (action or out) ----------------
__global__ void sync_update_kernel(const float* __restrict__ act, const int* __restrict__ la,
                                   const int* __restrict__ ra, const float* __restrict__ decay,
                                   float* __restrict__ a, float* __restrict__ bs,
                                   float* __restrict__ syncv) {
  int i = blockIdx.x * 256 + threadIdx.x;  // B*NSYNC
  if (i >= B_ * NSYNC) return;
  int b = i >> 9, j = i & (NSYNC - 1);
  float r = expf(-fminf(fmaxf(decay[j], 0.f), 15.f));
  float p = act[b * DMODEL + la[j]] * act[b * DMODEL + ra[j]];
  float av = r * a[i] + p;
  float bv = r * bs[i] + 1.f;
  a[i] = av;
  bs[i] = bv;
  syncv[i] = av / sqrtf(bv);
}

// ---------------- fused attention: scores + softmax + PV, one block per (b,h) ----------------
__global__ __launch_bounds__(256) void attn_kernel(const float* __restrict__ qh,
                                                   const __hip_bfloat16* __restrict__ kh,
                                                   const __hip_bfloat16* __restrict__ vh,
                                                   float* __restrict__ attn_v) {
  const int bh = blockIdx.x;
  const int b = bh >> 4, h = bh & (NH - 1);
  const int tid = threadIdx.x;
  __shared__ float qs[DH];
  __shared__ float w[S_];
  __shared__ float red[256];
  if (tid < DH) qs[tid] = qh[b * DIN + h * DH + tid];
  __syncthreads();
  float sc[2];
#pragma unroll
  for (int r = 0; r < 2; ++r) {
    int s = tid + r * 256;
    const unsigned* kp = reinterpret_cast<const unsigned*>(kh + ((size_t)(b * S_ + s) * DIN + h * DH));
    float accv = 0.f;
#pragma unroll
    for (int q = 0; q < DH / 2; ++q) {
      unsigned u = kp[q];
      accv += qs[q * 2 + 0] * bf_lo(u) + qs[q * 2 + 1] * bf_hi(u);
    }
    sc[r] = accv * 0.125f;  // 1/sqrt(64)
  }
  // max
  red[tid] = fmaxf(sc[0], sc[1]);
  __syncthreads();
  for (int st = 128; st > 0; st >>= 1) {
    if (tid < st) red[tid] = fmaxf(red[tid], red[tid + st]);
    __syncthreads();
  }
  const float mx = red[0];
  __syncthreads();
  float e0 = expf(sc[0] - mx), e1 = expf(sc[1] - mx);
  w[tid] = e0;
  w[tid + 256] = e1;
  red[tid] = e0 + e1;
  __syncthreads();
  for (int st = 128; st > 0; st >>= 1) {
    if (tid < st) red[tid] += red[tid + st];
    __syncthreads();
  }
  const float invZ = 1.f / red[0];
  __syncthreads();
  // PV: thread t -> d = t&63, s-group g = t>>6 (4 groups)
  const int d = tid & 63, g = tid >> 6;
  const __hip_bfloat16* vp = vh + ((size_t)b * S_ * DIN + (size_t)h * DH + d);
  float accv = 0.f;
  for (int s = g; s < S_; s += 4) accv += w[s] * __bfloat162float(vp[(size_t)s * DIN]);
  red[tid] = accv;
  __syncthreads();
  if (tid < 64) {
    float r = red[tid] + red[64 + tid] + red[128 + tid] + red[192 + tid];
    attn_v[b * DIN + h * DH + tid] = r * invZ;
  }
}

// ---------------- pre = concat(attn_o, act) ----------------
__global__ void pack_pre_kernel(const float* __restrict__ attn_o, const float* __restrict__ act,
                                float* __restrict__ pre) {
  int i = blockIdx.x * 256 + threadIdx.x;  // B * 3072
  if (i >= B_ * (DIN + DMODEL)) return;
  int b = i / (DIN + DMODEL);
  int c = i % (DIN + DMODEL);
  pre[i] = (c < DIN) ? attn_o[b * DIN + c] : act[b * DMODEL + (c - DIN)];
}

// ---------------- per-neuron NLM: out[b,d] = sum_h relu(b1 + hist·W1)·W2 + b2 ----------------
__global__ __launch_bounds__(256) void nlm_kernel(const float* __restrict__ hist,
                                                  const float* __restrict__ W1,
                                                  const float* __restrict__ b1,
                                                  const float* __restrict__ W2,
                                                  const float* __restrict__ b2,
                                                  float* __restrict__ out, int t) {
  const int tid = threadIdx.x;
  const int b = tid & 63;
  const int d = blockIdx.x * 4 + (tid >> 6);
  const float* hw = hist + ((size_t)b * DMODEL + d) * HIST_W + (t + 1);
  float win[DMEM];
#pragma unroll
  for (int m = 0; m < DMEM; ++m) win[m] = hw[m];
  const float* w1 = W1 + (size_t)d * DMEM * HNLM;
  const float* w2 = W2 + d * HNLM;
  const float* bb = b1 + d * HNLM;
  float acc = 0.f;
  for (int h = 0; h < HNLM; ++h) {
    float s = bb[h];
#pragma unroll
    for (int m = 0; m < DMEM; ++m) s += win[m] * w1[m * HNLM + h];
    acc += fmaxf(s, 0.f) * w2[h];
  }
  out[b * DMODEL + d] = acc + b2[d];
}

// ---------------- output head: log-softmax entropy + strided writes ----------------
__global__ __launch_bounds__(256) void out_kernel(const float* __restrict__ pred,
                                                  float* __restrict__ out, int t) {
  const int b = blockIdx.x;
  const int tid = threadIdx.x;
  const float* p = pred + b * DOUT;
  __shared__ float red[256];
  float m = -1e30f;
  for (int o = tid; o < DOUT; o += 256) m = fmaxf(m, p[o]);
  red[tid] = m;
  __syncthreads();
  for (int st = 128; st > 0; st >>= 1) {
    if (tid < st) red[tid] = fmaxf(red[tid], red[tid + st]);
    __syncthreads();
  }
  m = red[0];
  __syncthreads();
  float z = 0.f, s1 = 0.f;
  for (int o = tid; o < DOUT; o += 256) {
    float wv = p[o] - m;
    float e = expf(wv);
    z += e;
    s1 += e * wv;
  }
  red[tid] = z;
  __syncthreads();
  for (int st = 128; st > 0; st >>= 1) {
    if (tid < st) red[tid] += red[tid + st];
    __syncthreads();
  }
  const float Z = red[0];
  __syncthreads();
  red[tid] = s1;
  __syncthreads();
  for (int st = 128; st > 0; st >>= 1) {
    if (tid < st) red[tid] += red[tid + st];
    __syncthreads();
  }
  const float S1 = red[0];
  // sum p*logp = S1/Z - log(Z); ne = -that / log(DOUT)
  const float ne = -(S1 / Z - logf(Z)) / 6.907755278982137f;
  for (int o = tid; o < DOUT; o += 256) out[((size_t)b * DOUT + o) * TICKS + t] = p[o];
  if (tid == 0) {
    float* c = out + (size_t)B_ * DOUT * TICKS;
    c[b * 2 * TICKS + t] = ne;
    c[b * 2 * TICKS + TICKS + t] = 1.f - ne;
  }
}

// ---------------------------------------------------------------------------
extern "C" void kernel_launch(void* const* d_in, const int* in_sizes, int n_in,
                              void* d_out, int out_size, void* d_ws, size_t ws_size,
                              hipStream_t stream) {
  const float* x = (const float*)d_in[0];
  const float* W_kv = (const float*)d_in[1];
  const float* b_kv = (const float*)d_in[2];
  const float* g_kv = (const float*)d_in[3];
  const float* be_kv = (const float*)d_in[4];
  const float* W_q = (const float*)d_in[5];
  const float* b_q = (const float*)d_in[6];
  const float* W_aq = (const float*)d_in[7];
  const float* b_aq = (const float*)d_in[8];
  const float* W_ak = (const float*)d_in[9];
  const float* b_ak = (const float*)d_in[10];
  const float* W_av = (const float*)d_in[11];
  const float* b_av = (const float*)d_in[12];
  const float* W_ao = (const float*)d_in[13];
  const float* b_ao = (const float*)d_in[14];
  const float* W_s1 = (const float*)d_in[15];
  const float* b_s1 = (const float*)d_in[16];
  const float* W_s2 = (const float*)d_in[17];
  const float* b_s2 = (const float*)d_in[18];
  const float* g_s = (const float*)d_in[19];
  const float* be_s = (const float*)d_in[20];
  const float* W_n1 = (const float*)d_in[21];
  const float* b_n1 = (const float*)d_in[22];
  const float* W_n2 = (const float*)d_in[23];
  const float* b_n2 = (const float*)d_in[24];
  const float* g_n = (const float*)d_in[25];
  const float* be_n = (const float*)d_in[26];
  const float* init_state = (const float*)d_in[27];
  const float* init_hist = (const float*)d_in[28];
  const float* decay_action = (const float*)d_in[29];
  const float* decay_out = (const float*)d_in[30];
  const float* W_out = (const float*)d_in[31];
  const float* b_out = (const float*)d_in[32];
  const int* idx_la = (const int*)d_in[33];
  const int* idx_ra = (const int*)d_in[34];
  const int* idx_lo = (const int*)d_in[35];
  const int* idx_ro = (const int*)d_in[36];
  float* out = (float*)d_out;

  // ---- workspace carve ----
  char* wsb = (char*)d_ws;
  size_t off = 0;
  auto alloc = [&](size_t bytes) -> char* {
    char* p = wsb + off;
    off += (bytes + 255) & ~(size_t)255;
    return p;
  };
  const size_t MS = (size_t)B_ * S_;  // 32768
  char* regionA = alloc(MS * DIN * 4);                    // kvraw fp32; later kh+vh bf16
  __hip_bfloat16* kv = (__hip_bfloat16*)alloc(MS * DIN * 2);
  float* histf = (float*)alloc((size_t)B_ * DMODEL * HIST_W * 4);
  float* act = (float*)alloc((size_t)B_ * DMODEL * 4);
  float* aA = (float*)alloc((size_t)B_ * NSYNC * 4);
  float* bA = (float*)alloc((size_t)B_ * NSYNC * 4);
  float* aO = (float*)alloc((size_t)B_ * NSYNC * 4);
  float* bO = (float*)alloc((size_t)B_ * NSYNC * 4);
  float* syncA = (float*)alloc((size_t)B_ * NSYNC * 4);
  float* syncO = (float*)alloc((size_t)B_ * NSYNC * 4);
  float* qbuf = (float*)alloc((size_t)B_ * DIN * 4);
  float* qhb = (float*)alloc((size_t)B_ * DIN * 4);
  float* attnv = (float*)alloc((size_t)B_ * DIN * 4);
  float* attno = (float*)alloc((size_t)B_ * DIN * 4);
  float* pre = (float*)alloc((size_t)B_ * (DIN + DMODEL) * 4);
  float* h1 = (float*)alloc((size_t)B_ * DMODEL * 4);
  float* h2 = (float*)alloc((size_t)B_ * DMODEL * 4);
  float* nlmraw = (float*)alloc((size_t)B_ * DMODEL * 4);
  float* predb = (float*)alloc((size_t)B_ * DOUT * 4);

  float* kvraw = (float*)regionA;
  __hip_bfloat16* kh = (__hip_bfloat16*)regionA;
  __hip_bfloat16* vh = (__hip_bfloat16*)(regionA + MS * DIN * 2);

  // ---- precompute: kv = LN(x@W_kv+b_kv); kh = kv@W_ak+b_ak; vh = kv@W_av+b_av ----
  {
    dim3 g(DIN / 64, MS / 128);
    gemm_k<128, 64, 16, 8, 4, 0, float, float><<<g, 256, 0, stream>>>(
        x, W_kv, b_kv, kvraw, (int)MS, DIN, F_);
  }
  ln_kernel<__hip_bfloat16><<<(int)MS, 256, 0, stream>>>(kvraw, g_kv, be_kv, kv, DIN, DIN, 1);
  {
    dim3 g(DIN / 64, MS / 128);
    gemm_k<128, 64, 16, 8, 4, 0, __hip_bfloat16, __hip_bfloat16><<<g, 256, 0, stream>>>(
        kv, W_ak, b_ak, kh, (int)MS, DIN, DIN);
    gemm_k<128, 64, 16, 8, 4, 0, __hip_bfloat16, __hip_bfloat16><<<g, 256, 0, stream>>>(
        kv, W_av, b_av, vh, (int)MS, DIN, DIN);
  }

  // ---- state init ----
  init_act_kernel<<<(B_ * DMODEL + 255) / 256, 256, 0, stream>>>(init_state, act);
  init_hist_kernel<<<(B_ * DMODEL * DMEM + 255) / 256, 256, 0, stream>>>(init_hist, histf);
  init_sync_kernel<<<(B_ * NSYNC + 255) / 256, 256, 0, stream>>>(init_state, idx_lo, idx_ro,
                                                                 aA, bA, aO, bO);

  // ---- tick loop ----
  for (int t = 0; t < TICKS; ++t) {
    sync_update_kernel<<<(B_ * NSYNC + 255) / 256, 256, 0, stream>>>(
        act, idx_la, idx_ra, decay_action, aA, bA, syncA);
    gemm_k<64, 64, 16, 4, 4, 0, float, float><<<dim3(DIN / 64, 1), 256, 0, stream>>>(
        syncA, W_q, b_q, qbuf, B_, DIN, NSYNC);
    gemm_k<64, 64, 16, 4, 4, 0, float, float><<<dim3(DIN / 64, 1), 256, 0, stream>>>(
        qbuf, W_aq, b_aq, qhb, B_, DIN, DIN);
    attn_kernel<<<B_ * NH, 256, 0, stream>>>(qhb, kh, vh, attnv);
    gemm_k<64, 64, 16, 4, 4, 0, float, float><<<dim3(DIN / 64, 1), 256, 0, stream>>>(
        attnv, W_ao, b_ao, attno, B_, DIN, DIN);
    pack_pre_kernel<<<(B_ * (DIN + DMODEL) + 255) / 256, 256, 0, stream>>>(attno, act, pre);
    gemm_k<64, 64, 16, 4, 4, 1, float, float><<<dim3(DMODEL / 64, 1), 256, 0, stream>>>(
        pre, W_s1, b_s1, h1, B_, DMODEL, DIN + DMODEL);
    gemm_k<64, 64, 16, 4, 4, 0, float, float><<<dim3(DMODEL / 64, 1), 256, 0, stream>>>(
        h1, W_s2, b_s2, h2, B_, DMODEL, DMODEL);
    // pre_act -> hist slot (32+t)
    ln_kernel<float><<<B_, 256, 0, stream>>>(h2, g_s, be_s, histf + 32 + t, DMODEL,
                                             (size_t)DMODEL * HIST_W, HIST_W);
    nlm_kernel<<<DMODEL / 4, 256, 0, stream>>>(histf, W_n1, b_n1, W_n2, b_n2, nlmraw, t);
    ln_kernel<float><<<B_, 256, 0, stream>>>(nlmraw, g_n, be_n, act, DMODEL, DMODEL, 1);
    sync_update_kernel<<<(B_ * NSYNC + 255) / 256, 256, 0, stream>>>(
        act, idx_lo, idx_ro, decay_out, aO, bO, syncO);
    gemm_k<64, 64, 16, 4, 4, 0, float, float><<<dim3((DOUT + 63) / 64, 1), 256, 0, stream>>>(
        syncO, W_out, b_out, predb, B_, DOUT, NSYNC);
    out_kernel<<<B_, 256, 0, stream>>>(predb, out, t);
  }
  (void)in_sizes; (void)n_in; (void)out_size; (void)ws_size;
}

// Round 2
// 2891.292 us; speedup vs baseline: 10.8929x; 10.8929x over previous
//
#include <hip/hip_runtime.h>
#include <hip/hip_bf16.h>

// ---------------------------------------------------------------------------
// CTM round 1: MFMA bf16 GEMMs (big 128x128 tile + split-K skinny M=64),
// W_q@W_aq fusion, bf16 weight transposes. fp32 recurrent state/LN/NLM.
// ---------------------------------------------------------------------------

#define B_ 64
#define S_ 512
#define F_ 1024
#define DMODEL 2048
#define DMEM 32
#define DIN 1024
#define NH 16
#define DH 64
#define DOUT 1000
#define NSYNC 512
#define TICKS 16
#define HNLM 32
#define HIST_W 48

typedef __attribute__((ext_vector_type(8))) short short8;
typedef __attribute__((ext_vector_type(4))) float f32x4;

__device__ inline void store_f(float* p, float v) { *p = v; }
__device__ inline void store_f(__hip_bfloat16* p, float v) { *p = __float2bfloat16(v); }

__device__ inline short f2bs(float f) {
  __hip_bfloat16 h = __float2bfloat16(f);
  return *reinterpret_cast<short*>(&h);
}

__device__ inline float gelu_f(float x) {
  float x3 = x * x * x;
  return 0.5f * x * (1.f + tanhf(0.7978845608028654f * (x + 0.044715f * x3)));
}

__device__ inline float bf_lo(unsigned v) { return __uint_as_float(v << 16); }
__device__ inline float bf_hi(unsigned v) { return __uint_as_float(v & 0xffff0000u); }

// ---------------- weight prep ----------------
// W (K,N) fp32 -> Wt (Npad,K) bf16, zero pad for n>=N
__global__ __launch_bounds__(256) void transpose_bf16_kernel(const float* __restrict__ W,
                                                             __hip_bfloat16* __restrict__ Wt,
                                                             int K, int N, int Npad) {
  __shared__ float t[32][33];
  const int tx = threadIdx.x, ty = threadIdx.y;  // 32 x 8
  const int n0 = blockIdx.x * 32, k0 = blockIdx.y * 32;
#pragma unroll
  for (int i = 0; i < 4; i++) {
    int k = k0 + ty + i * 8;
    t[ty + i * 8][tx] = (k < K && n0 + tx < N) ? W[(size_t)k * N + n0 + tx] : 0.f;
  }
  __syncthreads();
#pragma unroll
  for (int i = 0; i < 4; i++) {
    int n = n0 + ty + i * 8;
    if (n < Npad && k0 + tx < K)
      Wt[(size_t)n * K + k0 + tx] = __float2bfloat16(t[tx][ty + i * 8]);
  }
}

__global__ void conv_bf16_kernel(const float* __restrict__ src, __hip_bfloat16* __restrict__ dst,
                                 int n) {
  int i = blockIdx.x * 256 + threadIdx.x;
  if (i < n) dst[i] = __float2bfloat16(src[i]);
}

__global__ void pad_bias_kernel(const float* __restrict__ b, float* __restrict__ bp, int n,
                                int np) {
  int i = blockIdx.x * 256 + threadIdx.x;
  if (i < np) bp[i] = (i < n) ? b[i] : 0.f;
}

// b_qaq[n] = b_aq[n] + sum_k b_q[k] * W_aq[k][n]  (via Wt_aq rows)
__global__ void bqaq_kernel(const float* __restrict__ b_q, const float* __restrict__ b_aq,
                            const __hip_bfloat16* __restrict__ Wt_aq, float* __restrict__ b_qaq) {
  int n = blockIdx.x * 256 + threadIdx.x;
  if (n >= DIN) return;
  const __hip_bfloat16* wr = Wt_aq + (size_t)n * DIN;
  float s = b_aq[n];
  for (int k = 0; k < DIN; k++) s += b_q[k] * __bfloat162float(wr[k]);
  b_qaq[n] = s;
}

// ---------------- big MFMA GEMM: C[M,N] = A[M,K] @ Bt[N,K]^T (+bias) ----------------
// 128x128 tile, BK=64, 256 thr = 4 waves (2x2), wave tile 64x64. M%128==0, N%128==0, K%64==0.
__device__ inline short8 load_chunk(const __hip_bfloat16* p) {
  return *reinterpret_cast<const short8*>(p);
}
__device__ inline short8 load_chunk(const float* p) {
  short8 r;
#pragma unroll
  for (int j = 0; j < 8; j++) r[j] = f2bs(p[j]);
  return r;
}

template <int TRANSC, typename TA, typename TC>
__global__ __launch_bounds__(256) void gemm_big(const TA* __restrict__ A,
                                                const __hip_bfloat16* __restrict__ Bt,
                                                const float* __restrict__ bias,
                                                TC* __restrict__ C, int M, int N, int K) {
  __shared__ short lsA[128 * 64];
  __shared__ short lsB[128 * 64];
  const int tid = threadIdx.x;
  const int l = tid & 63, w = tid >> 6;
  const int wr = (w >> 1) * 64, wc = (w & 1) * 64;
  const int brow = blockIdx.y * 128, bcol = blockIdx.x * 128;
  f32x4 acc[4][4];
#pragma unroll
  for (int i = 0; i < 4; i++)
#pragma unroll
    for (int j = 0; j < 4; j++)
#pragma unroll
      for (int r = 0; r < 4; r++) acc[i][j][r] = 0.f;

  short8 ra[4], rb[4];
  auto gload = [&](int k0) {
#pragma unroll
    for (int q = 0; q < 4; q++) {
      int i = tid + q * 256;
      int row = i >> 3, c = i & 7;
      ra[q] = load_chunk(A + (size_t)(brow + row) * K + k0 + c * 8);
      rb[q] = load_chunk(Bt + (size_t)(bcol + row) * K + k0 + c * 8);
    }
  };
  auto lwrite = [&]() {
#pragma unroll
    for (int q = 0; q < 4; q++) {
      int i = tid + q * 256;
      int row = i >> 3, c = i & 7;
      int sw = c ^ (row & 7);
      *reinterpret_cast<short8*>(&lsA[row * 64 + sw * 8]) = ra[q];
      *reinterpret_cast<short8*>(&lsB[row * 64 + sw * 8]) = rb[q];
    }
  };
  gload(0);
  for (int k0 = 0; k0 < K; k0 += 64) {
    __syncthreads();
    lwrite();
    if (k0 + 64 < K) gload(k0 + 64);
    __syncthreads();
#pragma unroll
    for (int ks = 0; ks < 2; ks++) {
      short8 af[4], bfv[4];
#pragma unroll
      for (int mi = 0; mi < 4; mi++) {
        int row = wr + mi * 16 + (l & 15);
        int c = ks * 4 + (l >> 4);
        af[mi] = *reinterpret_cast<const short8*>(&lsA[row * 64 + (c ^ (row & 7)) * 8]);
      }
#pragma unroll
      for (int ni = 0; ni < 4; ni++) {
        int row = wc + ni * 16 + (l & 15);
        int c = ks * 4 + (l >> 4);
        bfv[ni] = *reinterpret_cast<const short8*>(&lsB[row * 64 + (c ^ (row & 7)) * 8]);
      }
#pragma unroll
      for (int mi = 0; mi < 4; mi++)
#pragma unroll
        for (int ni = 0; ni < 4; ni++)
          acc[mi][ni] =
              __builtin_amdgcn_mfma_f32_16x16x32_bf16(af[mi], bfv[ni], acc[mi][ni], 0, 0, 0);
    }
  }
#pragma unroll
  for (int mi = 0; mi < 4; mi++)
#pragma unroll
    for (int ni = 0; ni < 4; ni++)
#pragma unroll
      for (int r = 0; r < 4; r++) {
        int row = brow + wr + mi * 16 + (l >> 4) * 4 + r;
        int col = bcol + wc + ni * 16 + (l & 15);
        float v = acc[mi][ni][r];
        if (bias) v += bias[col];
        if (TRANSC)
          store_f(&C[(size_t)col * M + row], v);
        else
          store_f(&C[(size_t)row * N + col], v);
      }
}

// ---------------- skinny split-K MFMA GEMM: M=64 ----------------
// grid (N/64, KS); partial[ks][64][N] = A[64, kchunk] @ Bt-chunk^T
__global__ __launch_bounds__(256) void gemm_skinny(const __hip_bfloat16* __restrict__ A,
                                                   const __hip_bfloat16* __restrict__ Bt,
                                                   float* __restrict__ part, int N, int K,
                                                   int kchunk) {
  __shared__ short lsA[64 * 64];
  __shared__ short lsB[64 * 64];
  const int tid = threadIdx.x;
  const int l = tid & 63, w = tid >> 6;
  const int bcol = blockIdx.x * 64;
  const int kb = blockIdx.y * kchunk;
  f32x4 acc[4];
#pragma unroll
  for (int i = 0; i < 4; i++)
#pragma unroll
    for (int r = 0; r < 4; r++) acc[i][r] = 0.f;

  short8 ra[2], rb[2];
  auto gload = [&](int k0) {
#pragma unroll
    for (int q = 0; q < 2; q++) {
      int i = tid + q * 256;
      int row = i >> 3, c = i & 7;
      ra[q] = *reinterpret_cast<const short8*>(A + (size_t)row * K + k0 + c * 8);
      rb[q] = *reinterpret_cast<const short8*>(Bt + (size_t)(bcol + row) * K + k0 + c * 8);
    }
  };
  auto lwrite = [&]() {
#pragma unroll
    for (int q = 0; q < 2; q++) {
      int i = tid + q * 256;
      int row = i >> 3, c = i & 7;
      int sw = c ^ (row & 7);
      *reinterpret_cast<short8*>(&lsA[row * 64 + sw * 8]) = ra[q];
      *reinterpret_cast<short8*>(&lsB[row * 64 + sw * 8]) = rb[q];
    }
  };
  gload(kb);
  for (int k0 = kb; k0 < kb + kchunk; k0 += 64) {
    __syncthreads();
    lwrite();
    if (k0 + 64 < kb + kchunk) gload(k0 + 64);
    __syncthreads();
#pragma unroll
    for (int ks = 0; ks < 2; ks++) {
      int rowa = w * 16 + (l & 15);
      int c = ks * 4 + (l >> 4);
      short8 af = *reinterpret_cast<const short8*>(&lsA[rowa * 64 + (c ^ (rowa & 7)) * 8]);
#pragma unroll
      for (int ni = 0; ni < 4; ni++) {
        int rowb = ni * 16 + (l & 15);
        short8 bfv = *reinterpret_cast<const short8*>(&lsB[rowb * 64 + (c ^ (rowb & 7)) * 8]);
        acc[ni] = __builtin_amdgcn_mfma_f32_16x16x32_bf16(af, bfv, acc[ni], 0, 0, 0);
      }
    }
  }
#pragma unroll
  for (int ni = 0; ni < 4; ni++)
#pragma unroll
    for (int r = 0; r < 4; r++) {
      int m = w * 16 + (l >> 4) * 4 + r;
      int n = bcol + ni * 16 + (l & 15);
      part[((size_t)blockIdx.y * 64 + m) * N + n] = acc[ni][r];
    }
}

// reduce split-K partials + bias (+gelu), typed/strided output
template <int ACT, typename TOUT>
__global__ void reduce_kernel(const float* __restrict__ part, const float* __restrict__ bias,
                              TOUT* __restrict__ out, int N, int KS, int ostride) {
  int i = blockIdx.x * 256 + threadIdx.x;
  if (i >= 64 * N) return;
  int m = i / N, n = i % N;
  float s = 0.f;
  for (int k = 0; k < KS; k++) s += part[((size_t)k * 64 + m) * N + n];
  s += bias[n];
  if (ACT == 1) s = gelu_f(s);
  store_f(&out[(size_t)m * ostride + n], s);
}

// ---------------- LayerNorm over last dim; strided/typed output ----------------
template <typename TOUT>
__global__ __launch_bounds__(256) void ln_kernel(const float* __restrict__ x,
                                                 const float* __restrict__ g,
                                                 const float* __restrict__ be,
                                                 TOUT* __restrict__ out, int C,
                                                 size_t row_stride, int col_stride) {
  const int row = blockIdx.x;
  const int tid = threadIdx.x;
  const float* xr = x + (size_t)row * C;
  float s = 0.f, s2 = 0.f;
  for (int c = tid; c < C; c += 256) {
    float v = xr[c];
    s += v;
    s2 += v * v;
  }
  __shared__ float r1[256], r2[256];
  r1[tid] = s;
  r2[tid] = s2;
  __syncthreads();
  for (int st = 128; st > 0; st >>= 1) {
    if (tid < st) {
      r1[tid] += r1[tid + st];
      r2[tid] += r2[tid + st];
    }
    __syncthreads();
  }
  float mean = r1[0] / C;
  float var = r2[0] / C - mean * mean;
  float inv = 1.0f / sqrtf(var + 1e-5f);
  for (int c = tid; c < C; c += 256) {
    float v = (xr[c] - mean) * inv * g[c] + be[c];
    store_f(&out[(size_t)row * row_stride + (size_t)c * col_stride], v);
  }
}

// ---------------- init kernels ----------------
__global__ void init_act_kernel(const float* __restrict__ init_state, float* __restrict__ act) {
  int i = blockIdx.x * 256 + threadIdx.x;
  if (i < B_ * DMODEL) act[i] = init_state[i & (DMODEL - 1)];
}

__global__ void init_hist_kernel(const float* __restrict__ init_hist, float* __restrict__ hist) {
  int i = blockIdx.x * 256 + threadIdx.x;
  if (i >= B_ * DMODEL * DMEM) return;
  int m = i & (DMEM - 1);
  int bd = i >> 5;
  int d = bd & (DMODEL - 1);
  hist[(size_t)bd * HIST_W + m] = init_hist[d * DMEM + m];
}

__global__ void init_sync_kernel(const float* __restrict__ init_state,
                                 const int* __restrict__ lo, const int* __restrict__ ro,
                                 float* __restrict__ aA, float* __restrict__ bA,
                                 float* __restrict__ aO, float* __restrict__ bO) {
  int i = blockIdx.x * 256 + threadIdx.x;
  if (i >= B_ * NSYNC) return;
  int j = i & (NSYNC - 1);
  aA[i] = 0.f;
  bA[i] = 0.f;
  aO[i] = init_state[lo[j]] * init_state[ro[j]];
  bO[i] = 1.f;
}

// ---------------- sync accumulator update ----------------
__global__ void sync_update_kernel(const float* __restrict__ act, const int* __restrict__ la,
                                   const int* __restrict__ ra, const float* __restrict__ decay,
                                   float* __restrict__ a, float* __restrict__ bs,
                                   __hip_bfloat16* __restrict__ syncv) {
  int i = blockIdx.x * 256 + threadIdx.x;
  if (i >= B_ * NSYNC) return;
  int b = i >> 9, j = i & (NSYNC - 1);
  float r = expf(-fminf(fmaxf(decay[j], 0.f), 15.f));
  float p = act[b * DMODEL + la[j]] * act[b * DMODEL + ra[j]];
  float av = r * a[i] + p;
  float bv = r * bs[i] + 1.f;
  a[i] = av;
  bs[i] = bv;
  syncv[i] = __float2bfloat16(av / sqrtf(bv));
}

// ---------------- fused decode attention per (b,h) ----------------
__global__ __launch_bounds__(256) void attn_kernel(const float* __restrict__ qh,
                                                   const __hip_bfloat16* __restrict__ kh,
                                                   const __hip_bfloat16* __restrict__ vh,
                                                   __hip_bfloat16* __restrict__ attn_v) {
  const int bh = blockIdx.x;
  const int b = bh >> 4, h = bh & (NH - 1);
  const int tid = threadIdx.x;
  __shared__ float qs[DH];
  __shared__ float w[S_];
  __shared__ float red[256];
  if (tid < DH) qs[tid] = qh[b * DIN + h * DH + tid];
  __syncthreads();
  float sc[2];
#pragma unroll
  for (int r = 0; r < 2; ++r) {
    int s = tid + r * 256;
    const unsigned* kp =
        reinterpret_cast<const unsigned*>(kh + ((size_t)(b * S_ + s) * DIN + h * DH));
    float accv = 0.f;
#pragma unroll
    for (int q = 0; q < DH / 2; ++q) {
      unsigned u = kp[q];
      accv += qs[q * 2 + 0] * bf_lo(u) + qs[q * 2 + 1] * bf_hi(u);
    }
    sc[r] = accv * 0.125f;
  }
  red[tid] = fmaxf(sc[0], sc[1]);
  __syncthreads();
  for (int st = 128; st > 0; st >>= 1) {
    if (tid < st) red[tid] = fmaxf(red[tid], red[tid + st]);
    __syncthreads();
  }
  const float mx = red[0];
  __syncthreads();
  float e0 = expf(sc[0] - mx), e1 = expf(sc[1] - mx);
  w[tid] = e0;
  w[tid + 256] = e1;
  red[tid] = e0 + e1;
  __syncthreads();
  for (int st = 128; st > 0; st >>= 1) {
    if (tid < st) red[tid] += red[tid + st];
    __syncthreads();
  }
  const float invZ = 1.f / red[0];
  __syncthreads();
  const int d = tid & 63, g = tid >> 6;
  const __hip_bfloat16* vp = vh + ((size_t)b * S_ * DIN + (size_t)h * DH + d);
  float accv = 0.f;
  for (int s = g; s < S_; s += 4) accv += w[s] * __bfloat162float(vp[(size_t)s * DIN]);
  red[tid] = accv;
  __syncthreads();
  if (tid < 64) {
    float r = red[tid] + red[64 + tid] + red[128 + tid] + red[192 + tid];
    attn_v[b * DIN + h * DH + tid] = __float2bfloat16(r * invZ);
  }
}

// act (fp32) -> pre[:, 1024:3072] bf16
__global__ void pack_act_kernel(const float* __restrict__ act, __hip_bfloat16* __restrict__ pre) {
  int i = blockIdx.x * 256 + threadIdx.x;
  if (i >= B_ * DMODEL) return;
  int b = i >> 11, j = i & (DMODEL - 1);
  pre[(size_t)b * (DIN + DMODEL) + DIN + j] = __float2bfloat16(act[i]);
}

// ---------------- per-neuron NLM ----------------
__global__ __launch_bounds__(256) void nlm_kernel(const float* __restrict__ hist,
                                                  const float* __restrict__ W1,
                                                  const float* __restrict__ b1,
                                                  const float* __restrict__ W2,
                                                  const float* __restrict__ b2,
                                                  float* __restrict__ out, int t) {
  const int tid = threadIdx.x;
  const int b = tid & 63;
  const int d = blockIdx.x * 4 + (tid >> 6);
  const float* hw = hist + ((size_t)b * DMODEL + d) * HIST_W + (t + 1);
  float win[DMEM];
#pragma unroll
  for (int m = 0; m < DMEM; ++m) win[m] = hw[m];
  const float* w1 = W1 + (size_t)d * DMEM * HNLM;
  const float* w2 = W2 + d * HNLM;
  const float* bb = b1 + d * HNLM;
  float acc = 0.f;
  for (int h = 0; h < HNLM; ++h) {
    float s = bb[h];
#pragma unroll
    for (int m = 0; m < DMEM; ++m) s += win[m] * w1[m * HNLM + h];
    acc += fmaxf(s, 0.f) * w2[h];
  }
  out[b * DMODEL + d] = acc + b2[d];
}

// ---------------- output head ----------------
__global__ __launch_bounds__(256) void out_kernel(const float* __restrict__ pred,
                                                  float* __restrict__ out, int t) {
  const int b = blockIdx.x;
  const int tid = threadIdx.x;
  const float* p = pred + (size_t)b * 1024;
  __shared__ float red[256];
  float m = -1e30f;
  for (int o = tid; o < DOUT; o += 256) m = fmaxf(m, p[o]);
  red[tid] = m;
  __syncthreads();
  for (int st = 128; st > 0; st >>= 1) {
    if (tid < st) red[tid] = fmaxf(red[tid], red[tid + st]);
    __syncthreads();
  }
  m = red[0];
  __syncthreads();
  float z = 0.f, s1 = 0.f;
  for (int o = tid; o < DOUT; o += 256) {
    float wv = p[o] - m;
    float e = expf(wv);
    z += e;
    s1 += e * wv;
  }
  red[tid] = z;
  __syncthreads();
  for (int st = 128; st > 0; st >>= 1) {
    if (tid < st) red[tid] += red[tid + st];
    __syncthreads();
  }
  const float Z = red[0];
  __syncthreads();
  red[tid] = s1;
  __syncthreads();
  for (int st = 128; st > 0; st >>= 1) {
    if (tid < st) red[tid] += red[tid + st];
    __syncthreads();
  }
  const float S1 = red[0];
  const float ne = -(S1 / Z - logf(Z)) / 6.907755278982137f;
  for (int o = tid; o < DOUT; o += 256) out[((size_t)b * DOUT + o) * TICKS + t] = p[o];
  if (tid == 0) {
    float* c = out + (size_t)B_ * DOUT * TICKS;
    c[b * 2 * TICKS + t] = ne;
    c[b * 2 * TICKS + TICKS + t] = 1.f - ne;
  }
}

// ---------------------------------------------------------------------------
extern "C" void kernel_launch(void* const* d_in, const int* in_sizes, int n_in,
                              void* d_out, int out_size, void* d_ws, size_t ws_size,
                              hipStream_t stream) {
  const float* x = (const float*)d_in[0];
  const float* W_kv = (const float*)d_in[1];
  const float* b_kv = (const float*)d_in[2];
  const float* g_kv = (const float*)d_in[3];
  const float* be_kv = (const float*)d_in[4];
  const float* W_q = (const float*)d_in[5];
  const float* b_q = (const float*)d_in[6];
  const float* W_aq = (const float*)d_in[7];
  const float* b_aq = (const float*)d_in[8];
  const float* W_ak = (const float*)d_in[9];
  const float* b_ak = (const float*)d_in[10];
  const float* W_av = (const float*)d_in[11];
  const float* b_av = (const float*)d_in[12];
  const float* W_ao = (const float*)d_in[13];
  const float* b_ao = (const float*)d_in[14];
  const float* W_s1 = (const float*)d_in[15];
  const float* b_s1 = (const float*)d_in[16];
  const float* W_s2 = (const float*)d_in[17];
  const float* b_s2 = (const float*)d_in[18];
  const float* g_s = (const float*)d_in[19];
  const float* be_s = (const float*)d_in[20];
  const float* W_n1 = (const float*)d_in[21];
  const float* b_n1 = (const float*)d_in[22];
  const float* W_n2 = (const float*)d_in[23];
  const float* b_n2 = (const float*)d_in[24];
  const float* g_n = (const float*)d_in[25];
  const float* be_n = (const float*)d_in[26];
  const float* init_state = (const float*)d_in[27];
  const float* init_hist = (const float*)d_in[28];
  const float* decay_action = (const float*)d_in[29];
  const float* decay_out = (const float*)d_in[30];
  const float* W_out = (const float*)d_in[31];
  const float* b_out = (const float*)d_in[32];
  const int* idx_la = (const int*)d_in[33];
  const int* idx_ra = (const int*)d_in[34];
  const int* idx_lo = (const int*)d_in[35];
  const int* idx_ro = (const int*)d_in[36];
  float* out = (float*)d_out;

  // ---- workspace carve ----
  char* wsb = (char*)d_ws;
  size_t off = 0;
  auto alloc = [&](size_t bytes) -> char* {
    char* p = wsb + off;
    off += (bytes + 255) & ~(size_t)255;
    return p;
  };
  const size_t MS = (size_t)B_ * S_;  // 32768
  char* regionA = alloc(MS * DIN * 4);  // kvraw fp32; later kh+vh bf16
  __hip_bfloat16* kv = (__hip_bfloat16*)alloc(MS * DIN * 2);
  float* histf = (float*)alloc((size_t)B_ * DMODEL * HIST_W * 4);
  // bf16 weights (transposed to (N,K))
  __hip_bfloat16* Wt_kv = (__hip_bfloat16*)alloc((size_t)DIN * F_ * 2);
  __hip_bfloat16* Wt_ak = (__hip_bfloat16*)alloc((size_t)DIN * DIN * 2);
  __hip_bfloat16* Wt_av = (__hip_bfloat16*)alloc((size_t)DIN * DIN * 2);
  __hip_bfloat16* Wt_aq = (__hip_bfloat16*)alloc((size_t)DIN * DIN * 2);
  __hip_bfloat16* Wt_ao = (__hip_bfloat16*)alloc((size_t)DIN * DIN * 2);
  __hip_bfloat16* W_qb = (__hip_bfloat16*)alloc((size_t)NSYNC * DIN * 2);
  __hip_bfloat16* Wt_qaq = (__hip_bfloat16*)alloc((size_t)DIN * NSYNC * 2);
  __hip_bfloat16* Wt_s1 = (__hip_bfloat16*)alloc((size_t)DMODEL * (DIN + DMODEL) * 2);
  __hip_bfloat16* Wt_s2 = (__hip_bfloat16*)alloc((size_t)DMODEL * DMODEL * 2);
  __hip_bfloat16* Wt_out = (__hip_bfloat16*)alloc((size_t)1024 * NSYNC * 2);
  float* b_qaq = (float*)alloc(DIN * 4);
  float* b_outp = (float*)alloc(1024 * 4);
  float* partial = (float*)alloc((size_t)8 * 64 * DMODEL * 4);
  float* act = (float*)alloc((size_t)B_ * DMODEL * 4);
  float* aA = (float*)alloc((size_t)B_ * NSYNC * 4);
  float* bA = (float*)alloc((size_t)B_ * NSYNC * 4);
  float* aO = (float*)alloc((size_t)B_ * NSYNC * 4);
  float* bO = (float*)alloc((size_t)B_ * NSYNC * 4);
  __hip_bfloat16* syncA = (__hip_bfloat16*)alloc((size_t)B_ * NSYNC * 2);
  __hip_bfloat16* syncO = (__hip_bfloat16*)alloc((size_t)B_ * NSYNC * 2);
  float* qhb = (float*)alloc((size_t)B_ * DIN * 4);
  __hip_bfloat16* attnv = (__hip_bfloat16*)alloc((size_t)B_ * DIN * 2);
  __hip_bfloat16* pre = (__hip_bfloat16*)alloc((size_t)B_ * (DIN + DMODEL) * 2);
  __hip_bfloat16* h1 = (__hip_bfloat16*)alloc((size_t)B_ * DMODEL * 2);
  float* h2 = (float*)alloc((size_t)B_ * DMODEL * 4);
  float* nlmraw = (float*)alloc((size_t)B_ * DMODEL * 4);
  float* predb = (float*)alloc((size_t)B_ * 1024 * 4);

  float* kvraw = (float*)regionA;
  __hip_bfloat16* kh = (__hip_bfloat16*)regionA;
  __hip_bfloat16* vh = (__hip_bfloat16*)(regionA + MS * DIN * 2);

  dim3 t32x8(32, 8);
  // ---- weight prep ----
  transpose_bf16_kernel<<<dim3(F_ / 32, DIN / 32), t32x8, 0, stream>>>(W_kv, Wt_kv, F_, DIN, DIN);
  transpose_bf16_kernel<<<dim3(DIN / 32, DIN / 32), t32x8, 0, stream>>>(W_ak, Wt_ak, DIN, DIN, DIN);
  transpose_bf16_kernel<<<dim3(DIN / 32, DIN / 32), t32x8, 0, stream>>>(W_av, Wt_av, DIN, DIN, DIN);
  transpose_bf16_kernel<<<dim3(DIN / 32, DIN / 32), t32x8, 0, stream>>>(W_aq, Wt_aq, DIN, DIN, DIN);
  transpose_bf16_kernel<<<dim3(DIN / 32, DIN / 32), t32x8, 0, stream>>>(W_ao, Wt_ao, DIN, DIN, DIN);
  transpose_bf16_kernel<<<dim3(DMODEL / 32, (DIN + DMODEL) / 32), t32x8, 0, stream>>>(
      W_s1, Wt_s1, DIN + DMODEL, DMODEL, DMODEL);
  transpose_bf16_kernel<<<dim3(DMODEL / 32, DMODEL / 32), t32x8, 0, stream>>>(W_s2, Wt_s2, DMODEL,
                                                                              DMODEL, DMODEL);
  transpose_bf16_kernel<<<dim3(1024 / 32, NSYNC / 32), t32x8, 0, stream>>>(W_out, Wt_out, NSYNC,
                                                                           DOUT, 1024);
  conv_bf16_kernel<<<(NSYNC * DIN + 255) / 256, 256, 0, stream>>>(W_q, W_qb, NSYNC * DIN);
  pad_bias_kernel<<<4, 256, 0, stream>>>(b_out, b_outp, DOUT, 1024);
  bqaq_kernel<<<4, 256, 0, stream>>>(b_q, b_aq, Wt_aq, b_qaq);

  // ---- precompute ----
  gemm_big<0, float, float><<<dim3(DIN / 128, MS / 128), 256, 0, stream>>>(
      x, Wt_kv, b_kv, kvraw, (int)MS, DIN, F_);
  ln_kernel<__hip_bfloat16><<<(int)MS, 256, 0, stream>>>(kvraw, g_kv, be_kv, kv, DIN, DIN, 1);
  gemm_big<0, __hip_bfloat16, __hip_bfloat16><<<dim3(DIN / 128, MS / 128), 256, 0, stream>>>(
      kv, Wt_ak, b_ak, kh, (int)MS, DIN, DIN);
  gemm_big<0, __hip_bfloat16, __hip_bfloat16><<<dim3(DIN / 128, MS / 128), 256, 0, stream>>>(
      kv, Wt_av, b_av, vh, (int)MS, DIN, DIN);
  // Wt_qaq = (W_q @ W_aq)^T  (TRANSC epilogue)
  gemm_big<1, __hip_bfloat16, __hip_bfloat16><<<dim3(DIN / 128, NSYNC / 128), 256, 0, stream>>>(
      W_qb, Wt_aq, nullptr, Wt_qaq, NSYNC, DIN, DIN);

  // ---- state init ----
  init_act_kernel<<<(B_ * DMODEL + 255) / 256, 256, 0, stream>>>(init_state, act);
  init_hist_kernel<<<(B_ * DMODEL * DMEM + 255) / 256, 256, 0, stream>>>(init_hist, histf);
  init_sync_kernel<<<(B_ * NSYNC + 255) / 256, 256, 0, stream>>>(init_state, idx_lo, idx_ro, aA,
                                                                 bA, aO, bO);

  // ---- tick loop ----
  for (int t = 0; t < TICKS; ++t) {
    sync_update_kernel<<<(B_ * NSYNC + 255) / 256, 256, 0, stream>>>(act, idx_la, idx_ra,
                                                                     decay_action, aA, bA, syncA);
    // qh = syncA @ Wt_qaq^T + b_qaq   (K=512, KS=8, chunk 64)
    gemm_skinny<<<dim3(DIN / 64, 8), 256, 0, stream>>>(syncA, Wt_qaq, partial, DIN, NSYNC, 64);
    reduce_kernel<0, float><<<(64 * DIN + 255) / 256, 256, 0, stream>>>(partial, b_qaq, qhb, DIN,
                                                                        8, DIN);
    attn_kernel<<<B_ * NH, 256, 0, stream>>>(qhb, kh, vh, attnv);
    // attno = attnv @ W_ao + b_ao -> pre[:, :1024]  (K=1024, KS=8, chunk 128)
    gemm_skinny<<<dim3(DIN / 64, 8), 256, 0, stream>>>(attnv, Wt_ao, partial, DIN, DIN, 128);
    reduce_kernel<0, __hip_bfloat16><<<(64 * DIN + 255) / 256, 256, 0, stream>>>(
        partial, b_ao, pre, DIN, 8, DIN + DMODEL);
    pack_act_kernel<<<(B_ * DMODEL + 255) / 256, 256, 0, stream>>>(act, pre);
    // h1 = gelu(pre @ W_s1 + b_s1)  (K=3072, KS=8, chunk 384)
    gemm_skinny<<<dim3(DMODEL / 64, 8), 256, 0, stream>>>(pre, Wt_s1, partial, DMODEL,
                                                          DIN + DMODEL, 384);
    reduce_kernel<1, __hip_bfloat16><<<(64 * DMODEL + 255) / 256, 256, 0, stream>>>(
        partial, b_s1, h1, DMODEL, 8, DMODEL);
    // h2 = h1 @ W_s2 + b_s2  (K=2048, KS=8, chunk 256)
    gemm_skinny<<<dim3(DMODEL / 64, 8), 256, 0, stream>>>(h1, Wt_s2, partial, DMODEL, DMODEL, 256);
    reduce_kernel<0, float><<<(64 * DMODEL + 255) / 256, 256, 0, stream>>>(partial, b_s2, h2,
                                                                           DMODEL, 8, DMODEL);
    // pre_act -> hist slot (32+t)
    ln_kernel<float><<<B_, 256, 0, stream>>>(h2, g_s, be_s, histf + 32 + t, DMODEL,
                                             (size_t)DMODEL * HIST_W, HIST_W);
    nlm_kernel<<<DMODEL / 4, 256, 0, stream>>>(histf, W_n1, b_n1, W_n2, b_n2, nlmraw, t);
    ln_kernel<float><<<B_, 256, 0, stream>>>(nlmraw, g_n, be_n, act, DMODEL, DMODEL, 1);
    sync_update_kernel<<<(B_ * NSYNC + 255) / 256, 256, 0, stream>>>(act, idx_lo, idx_ro,
                                                                     decay_out, aO, bO, syncO);
    // pred = syncO @ W_out + b_out  (N=1024 padded, K=512, KS=4, chunk 128)
    gemm_skinny<<<dim3(1024 / 64, 4), 256, 0, stream>>>(syncO, Wt_out, partial, 1024, NSYNC, 128);
    reduce_kernel<0, float><<<(64 * 1024 + 255) / 256, 256, 0, stream>>>(partial, b_outp, predb,
                                                                         1024, 4, 1024);
    out_kernel<<<B_, 256, 0, stream>>>(predb, out, t);
  }
  (void)in_sizes; (void)n_in; (void)out_size; (void)ws_size;
}